// Round 6
// baseline (210.612 us; speedup 1.0000x reference)
//
#include <hip/hip_runtime.h>
#include <stdint.h>

// DynamicFc R11: R10 fused block, 8 -> 16 waves (1024 thr), grid stays 256.
//  R10 counters: Occ 21.6% (2 waves/SIMD), MfmaUtil 10.3, VALU 11, HBM 16%,
//  VGPR only 80 -- still latency-starved, far from every floor (MFMA ~10us,
//  HBM ~28us, L2 weight stream ~20us). This doubles TLP to 4 waves/SIMD
//  WITHOUT doubling the per-block weight L2 re-read (grid unchanged).
//  Per-wave ownership halves per phase via ct-split: wave=(pw 0..7, ctw 0..1);
//  hred/gred stay 8-partial x [32][32] (two waves share a partial slot but
//  write disjoint b-halves). Phase A: wave=(l-tile wid>>1, sample-tile wid&1).
//  Phase D: wave owns one 16-n chunk per nb. LDS unchanged 62464B.
//  __launch_bounds__(1024,4) -> 128 VGPR cap (R10 measured 80 at 2x state).
// B=8192, F=1024, LOW=128, MID=32. p1: j=l*32+m (j<4096), p2: j=4096+m*128+l.
// Fragment-major images: chunk(T,ks)[lane][8] = W[T*16+(lane&15)][ks*32+(lane>>4)*8..+8]

typedef __attribute__((ext_vector_type(8))) short bf16x8;
typedef __attribute__((ext_vector_type(4))) float f32x4;

#define MFMA(a, b, c) __builtin_amdgcn_mfma_f32_16x16x32_bf16((a), (b), (c), 0, 0, 0)

__device__ __forceinline__ ushort f2bf(float x) {
    union { float f; uint32_t u; } v; v.f = x;
    return (ushort)((v.u + 0x7FFFu + ((v.u >> 16) & 1u)) >> 16);
}
__device__ __forceinline__ ushort4 f2bf4(float4 v) {
    ushort4 o; o.x = f2bf(v.x); o.y = f2bf(v.y); o.z = f2bf(v.z); o.w = f2bf(v.w); return o;
}
__device__ __forceinline__ float bf2f(ushort u) {
    union { uint32_t i; float f; } v; v.i = ((uint32_t)u) << 16; return v.f;
}

// ---------------- K0: convert + fragment-major re-layout (verified) ----------------
__global__ __launch_bounds__(256) void k0_convert(
    const float* __restrict__ pgw, const float* __restrict__ wf,
    const float* __restrict__ wpf, const float* __restrict__ w2,
    ushort* __restrict__ pg_img, ushort* __restrict__ w_img, ushort* __restrict__ w2_img)
{
    int cid = blockIdx.x * 256 + threadIdx.x;   // 704*256 = 180224
    const float* src; ushort* dst;
    if (cid < 131072) {                                  // pg: 512*4*64
        int lane = cid & 63, ks = (cid >> 6) & 3, T = cid >> 8;
        int j = T * 16 + (lane & 15), k = ks * 32 + (lane >> 4) * 8;
        src = pgw + (size_t)j * 128 + k;
        dst = pg_img + (size_t)cid * 8;
    } else if (cid < 163840) {                           // wf/wpf: 2*8*32*64
        int c = cid - 131072;
        int lane = c & 63, ks = (c >> 6) & 31, lt = (c >> 11) & 7, mat = c >> 14;
        int l = lt * 16 + (lane & 15), k = ks * 32 + (lane >> 4) * 8;
        src = (mat ? wpf : wf) + (size_t)l * 1024 + k;
        dst = w_img + (size_t)c * 8;
    } else {                                             // w2: 64*4*64
        int c = cid - 163840;
        int lane = c & 63, ks = (c >> 6) & 3, nt = c >> 8;
        int n = nt * 16 + (lane & 15), k = ks * 32 + (lane >> 4) * 8;
        src = w2 + (size_t)n * 128 + k;
        dst = w2_img + (size_t)c * 8;
    }
    float4 a = ((const float4*)src)[0], b = ((const float4*)src)[1];
    ((ushort4*)dst)[0] = f2bf4(a);
    ((ushort4*)dst)[1] = f2bf4(b);
}

// ---------------- MEGA: one block = 32 samples end-to-end, 16 waves ----------------
// grid 256 x 1024 threads; 1 block/CU, 4 waves/SIMD.
__global__ __launch_bounds__(1024, 4) void mega(
    const float* __restrict__ f, const float* __restrict__ pf,
    const ushort* __restrict__ w_img, const float* __restrict__ bfb,
    const float* __restrict__ bpfb, const ushort* __restrict__ pg_img,
    const float* __restrict__ pgb, const ushort* __restrict__ w2_img,
    const float* __restrict__ b2, float* __restrict__ out)
{
    __shared__ __align__(16) char smem[62464];
    // region0 (0..36864): As 33280 | Tr 8704 | hred 32768 (+hl 4096 @32768) |
    //                     gred 32768 | Ls 36864  (phase-reused)
    ushort* As    = (ushort*)smem;              // [32][520]
    ushort* Tr    = (ushort*)smem;              // [32][136]
    float*  hred  = (float*)smem;               // [8][32][32]
    float*  hl    = (float*)(smem + 32768);     // [32][32]
    float*  gred  = (float*)smem;               // [8][32][32]
    float*  Ls    = (float*)smem;               // [32][288]
    ushort* flowT = (ushort*)(smem + 36864);    // [128][36] bf16 = 9216 B
    ushort* pfrag = (ushort*)(smem + 46080);    // 8 chunks * 512 = 8192 B
    ushort* gfrag = (ushort*)(smem + 54272);    // 8 chunks * 512 = 8192 B

    const int tid = threadIdx.x;
    const int lane = tid & 63, wid = tid >> 6;   // wid 0..15
    const int q = lane >> 4, r15 = lane & 15;
    const int pw = wid & 7, ctw = wid >> 3;      // partial-wave / b-half split
    const int b0 = blockIdx.x * 32;

    // ================= Phase A: f_low / pf_low projections =================
    // wave = (l-tile lt = wid>>1, sample-tile mt = wid&1); 16 waves = 8 lt x 2 mt.
    {
        const int lt = wid >> 1, mt = wid & 1;
#pragma unroll 1
        for (int mat = 0; mat < 2; mat++) {
            const float* src = mat ? pf : f;
            const float* bias_ptr = mat ? bpfb : bfb;
            float bias_v = bias_ptr[lt * 16 + r15];

            f32x4 c = (f32x4){0.f, 0.f, 0.f, 0.f};

#pragma unroll 1
            for (int kh = 0; kh < 2; kh++) {     // K halves of 512 (As 32x520)
                __syncthreads();                 // prior As readers done
                float4 v[4];
#pragma unroll
                for (int rr = 0; rr < 4; rr++) {
                    int row = rr * 8 + (tid >> 7);
                    v[rr] = *(const float4*)(src + (size_t)(b0 + row) * 1024 + kh * 512 + (tid & 127) * 4);
                }
#pragma unroll
                for (int rr = 0; rr < 4; rr++) {
                    int row = rr * 8 + (tid >> 7);
                    *(ushort4*)(As + row * 520 + (tid & 127) * 4) = f2bf4(v[rr]);
                }
                __syncthreads();
                const ushort* wb = w_img + (size_t)mat * 131072 + ((size_t)lt * 32 + kh * 16) * 512;
                bf16x8 wfr[4];
#pragma unroll
                for (int p = 0; p < 4; p++) wfr[p] = *(const bf16x8*)(wb + (size_t)p * 512 + lane * 8);
#pragma unroll
                for (int ks = 0; ks < 16; ks++) {      // full unroll, ring-4
                    const int cur = ks & 3;
                    bf16x8 a0 = *(const bf16x8*)(As + (size_t)(mt * 16 + r15) * 520 + ks * 32 + q * 8);
                    c = MFMA(a0, wfr[cur], c);
                    if (ks + 4 < 16)
                        wfr[cur] = *(const bf16x8*)(wb + (size_t)(ks + 4) * 512 + lane * 8);
                }
            }
            // C: row = b_local (mt*16 + q*4 + r), col = l (lt*16 + r15)
            if (mat == 0) {
                int l = lt * 16 + r15;
#pragma unroll
                for (int r = 0; r < 4; r++)
                    flowT[l * 36 + mt * 16 + q * 4 + r] = f2bf(c[r] + bias_v);
            } else {
                __syncthreads();   // all As reads done before Tr overwrites region0
                int l = lt * 16 + r15;
#pragma unroll
                for (int r = 0; r < 4; r++)
                    Tr[(mt * 16 + q * 4 + r) * 136 + l] = f2bf(c[r] + bias_v);
                __syncthreads();
                // emit pfrag: one chunk per wave, waves 0..7 (chunkid = wid = bt*4 + ks2)
                if (wid < 8) {
                    int bt = wid >> 2, ks2 = wid & 3;
                    int k0 = ks2 * 32 + (lane >> 4) * 8;
                    uint4 tv = *(const uint4*)(Tr + (size_t)(bt * 16 + (lane & 15)) * 136 + k0);
                    *(uint4*)(pfrag + (size_t)wid * 512 + lane * 8) = tv;
                }
            }
        }
    }
    __syncthreads();   // pfrag/flowT visible to all waves

    // ================= Phase B: h partials (all jg; wave = (pw, ctw)) =========
    bf16x8 bfr[4];     // pf_low fragments for this wave's b-half, held through B and C
#pragma unroll
    for (int ks = 0; ks < 4; ks++)
        bfr[ks] = *(const bf16x8*)(pfrag + (size_t)(ctw * 4 + ks) * 512 + lane * 8);

    f32x4 hacc[2];     // [m-half]
    hacc[0] = (f32x4){0.f, 0.f, 0.f, 0.f};
    hacc[1] = (f32x4){0.f, 0.f, 0.f, 0.f};

#pragma unroll 1
    for (int jg = 0; jg < 8; jg++) {
        const ushort* Tbase = pg_img + (size_t)(jg * 32 + pw * 4) * 2048;
        bf16x8 af[4][4];   // ALL 4 tiles up front: 16 x 1KB loads in flight
#pragma unroll
        for (int i = 0; i < 4; i++)
#pragma unroll
            for (int ks = 0; ks < 4; ks++)
                af[i][ks] = *(const bf16x8*)(Tbase + (size_t)i * 2048 + ks * 512 + lane * 8);
#pragma unroll
        for (int i = 0; i < 4; i++) {
            const int tl = pw * 4 + i;         // p1 tile index within jg (0..31)
            const int mh = i & 1;              // tl&1 (pw*4 even)
            const int l_loc = tl >> 1;
            f32x4 bv = *(const f32x4*)(pgb + (size_t)(jg * 32 + tl) * 16 + q * 4);
            f32x4 cc = (f32x4){0.f, 0.f, 0.f, 0.f};
#pragma unroll
            for (int ks = 0; ks < 4; ks++) cc = MFMA(af[i][ks], bfr[ks], cc);
            float s = bf2f(flowT[(jg * 16 + l_loc) * 36 + ctw * 16 + r15]);
#pragma unroll
            for (int r = 0; r < 4; r++) hacc[mh][r] += s * (cc[r] + bv[r]);
        }
    }
#pragma unroll
    for (int mh = 0; mh < 2; mh++)
#pragma unroll
        for (int r = 0; r < 4; r++)
            hred[pw * 1024 + (mh * 16 + q * 4 + r) * 32 + ctw * 16 + r15] = hacc[mh][r];
    __syncthreads();
    {   // 8-partial reduce + relu -> hl [32 m][32 b]; 1024 threads, 1 float each
        int m = tid >> 5, bc = tid & 31;
        float s = 0.f;
#pragma unroll
        for (int w = 0; w < 8; w++) s += hred[w * 1024 + m * 32 + bc];
        hl[m * 32 + bc] = fmaxf(s, 0.f);
    }
    __syncthreads();

    // ================= Phase C: g (all lg; wave = (pw, ctw), ring-4) ==========
#pragma unroll 1
    for (int lg = 0; lg < 4; lg++) {
        f32x4 gacc[2];   // [lt]
        gacc[0] = (f32x4){0.f, 0.f, 0.f, 0.f};
        gacc[1] = (f32x4){0.f, 0.f, 0.f, 0.f};
        bf16x8 af[4][4];
#pragma unroll
        for (int t = 0; t < 4; t++) {          // preload ti 0..3
            const int m = pw + 8 * (t >> 1), lt = t & 1;
            const ushort* ap = pg_img + (size_t)(256 + m * 8 + lg * 2 + lt) * 2048;
#pragma unroll
            for (int ks = 0; ks < 4; ks++)
                af[t][ks] = *(const bf16x8*)(ap + ks * 512 + lane * 8);
        }
#pragma unroll
        for (int ti = 0; ti < 8; ti++) {       // full unroll, ring-4
            const int cur = ti & 3;
            const int m = pw + 8 * (ti >> 1), lt = ti & 1;
            f32x4 bv = *(const f32x4*)(pgb + 4096 + (size_t)m * 128 + lg * 32 + lt * 16 + q * 4);
            f32x4 cc = (f32x4){0.f, 0.f, 0.f, 0.f};
#pragma unroll
            for (int ks = 0; ks < 4; ks++) cc = MFMA(af[cur][ks], bfr[ks], cc);
            float s = hl[m * 32 + ctw * 16 + r15];
#pragma unroll
            for (int r = 0; r < 4; r++) gacc[lt][r] += s * (cc[r] + bv[r]);
            if (ti + 4 < 8) {
                const int tn = ti + 4;
                const int mn = pw + 8 * (tn >> 1), ltn = tn & 1;
                const ushort* ap = pg_img + (size_t)(256 + mn * 8 + lg * 2 + ltn) * 2048;
#pragma unroll
                for (int ks = 0; ks < 4; ks++)
                    af[cur][ks] = *(const bf16x8*)(ap + ks * 512 + lane * 8);
            }
        }
#pragma unroll
        for (int lt = 0; lt < 2; lt++)
#pragma unroll
            for (int r = 0; r < 4; r++)
                gred[pw * 1024 + (lt * 16 + q * 4 + r) * 32 + ctw * 16 + r15] = gacc[lt][r];
        __syncthreads();
        if (tid < 128) {   // 8-partial reduce + emit gfrag chunk (bt, ks=lg)
            int bt = tid >> 6, ln = tid & 63;
            int b_loc = bt * 16 + (ln & 15);
            int l0 = (ln >> 4) * 8;
            ushort tmp[8];
#pragma unroll
            for (int e = 0; e < 8; e++) {
                const float* gp = gred + (size_t)(l0 + e) * 32 + b_loc;
                float s = 0.f;
#pragma unroll
                for (int w = 0; w < 8; w++) s += gp[w * 1024];
                tmp[e] = f2bf(s);
            }
            ushort4 lo = {tmp[0], tmp[1], tmp[2], tmp[3]};
            ushort4 hi = {tmp[4], tmp[5], tmp[6], tmp[7]};
            ushort* dst = gfrag + (size_t)(bt * 4 + lg) * 512 + ln * 8;
            ((ushort4*)dst)[0] = lo;
            ((ushort4*)dst)[1] = hi;
        }
        __syncthreads();   // gred reuse (and gfrag ready after last lg)
    }

    // ================= Phase D: out = g@W2^T + b2 + f + pf (wave owns 16 n/nb) =======
    bf16x8 afg[2][4];
#pragma unroll
    for (int mtl = 0; mtl < 2; mtl++)
#pragma unroll
        for (int ks = 0; ks < 4; ks++)
            afg[mtl][ks] = *(const bf16x8*)(gfrag + (size_t)(mtl * 4 + ks) * 512 + lane * 8);

#pragma unroll 1
    for (int nb = 0; nb < 4; nb++) {
        float bias_v = b2[nb * 256 + wid * 16 + r15];
        bf16x8 wfr2[4];
#pragma unroll
        for (int ks = 0; ks < 4; ks++)
            wfr2[ks] = *(const bf16x8*)(w2_img + (size_t)((nb * 16 + wid) * 4 + ks) * 512 + lane * 8);
#pragma unroll
        for (int mtl = 0; mtl < 2; mtl++) {
            f32x4 cc = (f32x4){0.f, 0.f, 0.f, 0.f};
#pragma unroll
            for (int ks = 0; ks < 4; ks++) cc = MFMA(afg[mtl][ks], wfr2[ks], cc);
            // nloc = wid*16 + r15: chunk = wid>>1, within = (wid&1)*16 + r15
#pragma unroll
            for (int r = 0; r < 4; r++)
                Ls[(size_t)(mtl * 16 + q * 4 + r) * 288 + (wid >> 1) * 36 + (wid & 1) * 16 + r15] = cc[r] + bias_v;
        }
        __syncthreads();
        {   // wave-contiguous epilogue: wave w rows w*2..+2, lane i <-> n0+4i
            const float* ls = Ls + (size_t)(wid * 2) * 288 + (lane >> 3) * 36 + (lane & 7) * 4;
            const int n0 = nb * 256;
#pragma unroll
            for (int rr = 0; rr < 2; rr++) {
                const int b = b0 + wid * 2 + rr;
                const size_t gbase = (size_t)b * 1024 + n0 + lane * 4;
                float4 lv = *(const float4*)(ls + rr * 288);
                float4 fa = *(const float4*)(f + gbase);
                float4 pa = *(const float4*)(pf + gbase);
                float4 o;
                o.x = lv.x + fa.x + pa.x; o.y = lv.y + fa.y + pa.y;
                o.z = lv.z + fa.z + pa.z; o.w = lv.w + fa.w + pa.w;
                *(float4*)(out + gbase) = o;
            }
        }
        __syncthreads();   // Ls reuse protection for next nb
    }
}

// ---------------- launch ----------------
extern "C" void kernel_launch(void* const* d_in, const int* in_sizes, int n_in,
                              void* d_out, int out_size, void* d_ws, size_t ws_size,
                              hipStream_t stream)
{
    const float* f    = (const float*)d_in[0];
    const float* pf   = (const float*)d_in[1];
    const float* wf   = (const float*)d_in[2];
    const float* bfb  = (const float*)d_in[3];
    const float* wpf  = (const float*)d_in[4];
    const float* bpfb = (const float*)d_in[5];
    const float* w2   = (const float*)d_in[6];
    const float* b2   = (const float*)d_in[7];
    const float* pgw  = (const float*)d_in[8];
    const float* pgb  = (const float*)d_in[9];

    char* ws = (char*)d_ws;
    ushort* pg_img = (ushort*)(ws + 0);          // 2 MB
    ushort* w_img  = (ushort*)(ws + 2097152);    // 512 KB
    ushort* w2_img = (ushort*)(ws + 2621440);    // 256 KB
    float*  out    = (float*)d_out;

    k0_convert<<<dim3(704), dim3(256), 0, stream>>>(pgw, wf, wpf, w2, pg_img, w_img, w2_img);
    mega<<<dim3(256), dim3(1024), 0, stream>>>(f, pf, w_img, bfb, bpfb,
                                               pg_img, pgb, w2_img, b2, out);
}

// Round 7
// 176.478 us; speedup vs baseline: 1.1934x; 1.1934x over previous
//
#include <hip/hip_runtime.h>
#include <stdint.h>

// DynamicFc R12: R10 shape (512 thr, grid 256, verified 86us) + deep software
// pipelining. R11 post-mortem: 16-wave block -> compiler chased 2-blk/CU occ,
// VGPR 64, fragment arrays spilled (WRITE 58MB vs 33 ideal) => occupancy gain
// eaten by scratch traffic; net-of-spill TLP was NEUTRAL -> the stall is
// dependent-chain latency inside barrier-lockstep phases, so hide it with ILP:
//  A: prefetch next (mat,kh) stage into regs before current MFMA block
//  B: flatten jg x 4 tiles -> 32-tile stream, cross-boundary ring-4 af+bv
//  C: flatten lg x 8 tiles -> 32-tile stream, cross-boundary ring-4 af+bv
//  D: w2 fragments double-buffered across nb; epilogue f/pf loads issued at
//     nb top (land before the post-Ls barrier)
// All ring indices static via full unroll (rule #20). __launch_bounds__(512,2)
// -> 256 VGPR cap; est ~150-200 live. Spill tripwire = WRITE_SIZE >> 33MB.
// B=8192, F=1024, LOW=128, MID=32. p1: j=l*32+m (j<4096), p2: j=4096+m*128+l.
// Fragment-major images: chunk(T,ks)[lane][8] = W[T*16+(lane&15)][ks*32+(lane>>4)*8..+8]

typedef __attribute__((ext_vector_type(8))) short bf16x8;
typedef __attribute__((ext_vector_type(4))) float f32x4;

#define MFMA(a, b, c) __builtin_amdgcn_mfma_f32_16x16x32_bf16((a), (b), (c), 0, 0, 0)

__device__ __forceinline__ ushort f2bf(float x) {
    union { float f; uint32_t u; } v; v.f = x;
    return (ushort)((v.u + 0x7FFFu + ((v.u >> 16) & 1u)) >> 16);
}
__device__ __forceinline__ ushort4 f2bf4(float4 v) {
    ushort4 o; o.x = f2bf(v.x); o.y = f2bf(v.y); o.z = f2bf(v.z); o.w = f2bf(v.w); return o;
}
__device__ __forceinline__ float bf2f(ushort u) {
    union { uint32_t i; float f; } v; v.i = ((uint32_t)u) << 16; return v.f;
}

// ---------------- K0: convert + fragment-major re-layout (verified) ----------------
__global__ __launch_bounds__(256) void k0_convert(
    const float* __restrict__ pgw, const float* __restrict__ wf,
    const float* __restrict__ wpf, const float* __restrict__ w2,
    ushort* __restrict__ pg_img, ushort* __restrict__ w_img, ushort* __restrict__ w2_img)
{
    int cid = blockIdx.x * 256 + threadIdx.x;   // 704*256 = 180224
    const float* src; ushort* dst;
    if (cid < 131072) {                                  // pg: 512*4*64
        int lane = cid & 63, ks = (cid >> 6) & 3, T = cid >> 8;
        int j = T * 16 + (lane & 15), k = ks * 32 + (lane >> 4) * 8;
        src = pgw + (size_t)j * 128 + k;
        dst = pg_img + (size_t)cid * 8;
    } else if (cid < 163840) {                           // wf/wpf: 2*8*32*64
        int c = cid - 131072;
        int lane = c & 63, ks = (c >> 6) & 31, lt = (c >> 11) & 7, mat = c >> 14;
        int l = lt * 16 + (lane & 15), k = ks * 32 + (lane >> 4) * 8;
        src = (mat ? wpf : wf) + (size_t)l * 1024 + k;
        dst = w_img + (size_t)c * 8;
    } else {                                             // w2: 64*4*64
        int c = cid - 163840;
        int lane = c & 63, ks = (c >> 6) & 3, nt = c >> 8;
        int n = nt * 16 + (lane & 15), k = ks * 32 + (lane >> 4) * 8;
        src = w2 + (size_t)n * 128 + k;
        dst = w2_img + (size_t)c * 8;
    }
    float4 a = ((const float4*)src)[0], b = ((const float4*)src)[1];
    ((ushort4*)dst)[0] = f2bf4(a);
    ((ushort4*)dst)[1] = f2bf4(b);
}

// ---------------- MEGA: one block = 32 samples end-to-end, 8 waves ----------------
// grid 256 x 512 threads; 1 block/CU, 2 waves/SIMD, deep per-wave pipelining.
__global__ __launch_bounds__(512, 2) void mega(
    const float* __restrict__ f, const float* __restrict__ pf,
    const ushort* __restrict__ w_img, const float* __restrict__ bfb,
    const float* __restrict__ bpfb, const ushort* __restrict__ pg_img,
    const float* __restrict__ pgb, const ushort* __restrict__ w2_img,
    const float* __restrict__ b2, float* __restrict__ out)
{
    __shared__ __align__(16) char smem[62464];
    // region0 (0..36864): As 33280 | Tr 8704 | hred 32768 (+hl 4096 @32768) |
    //                     gred 32768 | Ls 36864  (phase-reused)
    ushort* As    = (ushort*)smem;              // [32][520]
    ushort* Tr    = (ushort*)smem;              // [32][136]
    float*  hred  = (float*)smem;               // [8][32][32]
    float*  hl    = (float*)(smem + 32768);     // [32][32]
    float*  gred  = (float*)smem;               // [8][32][32]
    float*  Ls    = (float*)smem;               // [32][288]
    ushort* flowT = (ushort*)(smem + 36864);    // [128][36] bf16 = 9216 B
    ushort* pfrag = (ushort*)(smem + 46080);    // 8 chunks * 512 = 8192 B
    ushort* gfrag = (ushort*)(smem + 54272);    // 8 chunks * 512 = 8192 B

    const int tid = threadIdx.x;
    const int lane = tid & 63, wid = tid >> 6;   // wid 0..7
    const int q = lane >> 4, r15 = lane & 15;
    const int b0 = blockIdx.x * 32;

    // ================= Phase A: f_low / pf_low projections (stage-pipelined) ========
    {
        float4 vbuf[8];
        // preload stage 0 (mat=0, kh=0)
#pragma unroll
        for (int rr = 0; rr < 8; rr++) {
            int row = rr * 4 + (tid >> 7);
            vbuf[rr] = *(const float4*)(f + (size_t)(b0 + row) * 1024 + (tid & 127) * 4);
        }
        f32x4 c[2];
        float bias_v = 0.f;
#pragma unroll
        for (int s = 0; s < 4; s++) {            // (mat,kh) = (0,0)(0,1)(1,0)(1,1)
            const int mat = s >> 1, kh = s & 1;
            if (kh == 0) {
                c[0] = (f32x4){0.f, 0.f, 0.f, 0.f};
                c[1] = (f32x4){0.f, 0.f, 0.f, 0.f};
                bias_v = (mat ? bpfb : bfb)[wid * 16 + r15];
            }
            __syncthreads();                     // prior As readers done
#pragma unroll
            for (int rr = 0; rr < 8; rr++) {
                int row = rr * 4 + (tid >> 7);
                *(ushort4*)(As + row * 520 + (tid & 127) * 4) = f2bf4(vbuf[rr]);
            }
            __syncthreads();
            if (s < 3) {                         // issue NEXT stage loads (hide HBM)
                const int sn = s + 1, matn = sn >> 1, khn = sn & 1;
                const float* srcn = matn ? pf : f;
#pragma unroll
                for (int rr = 0; rr < 8; rr++) {
                    int row = rr * 4 + (tid >> 7);
                    vbuf[rr] = *(const float4*)(srcn + (size_t)(b0 + row) * 1024 + khn * 512 + (tid & 127) * 4);
                }
            }
            const ushort* wb = w_img + (size_t)mat * 131072 + ((size_t)wid * 32 + kh * 16) * 512;
            bf16x8 wfr[4];
#pragma unroll
            for (int p = 0; p < 4; p++) wfr[p] = *(const bf16x8*)(wb + (size_t)p * 512 + lane * 8);
#pragma unroll
            for (int ks = 0; ks < 16; ks++) {    // full unroll, ring-4
                const int cur = ks & 3;
                bf16x8 a0 = *(const bf16x8*)(As + (size_t)r15 * 520 + ks * 32 + q * 8);
                bf16x8 a1 = *(const bf16x8*)(As + (size_t)(16 + r15) * 520 + ks * 32 + q * 8);
                c[0] = MFMA(a0, wfr[cur], c[0]);
                c[1] = MFMA(a1, wfr[cur], c[1]);
                if (ks + 4 < 16)
                    wfr[cur] = *(const bf16x8*)(wb + (size_t)(ks + 4) * 512 + lane * 8);
            }
            // C: row = b_local (mt*16 + q*4 + r), col = l (wid*16 + r15)
            if (s == 1) {                        // mat0 epilogue -> flowT (disjoint)
                int l = wid * 16 + r15;
#pragma unroll
                for (int mt = 0; mt < 2; mt++)
#pragma unroll
                    for (int r = 0; r < 4; r++)
                        flowT[l * 36 + mt * 16 + q * 4 + r] = f2bf(c[mt][r] + bias_v);
            }
            if (s == 3) {                        // mat1 epilogue -> Tr -> pfrag
                __syncthreads();                 // all As reads done before Tr overwrite
                int l = wid * 16 + r15;
#pragma unroll
                for (int mt = 0; mt < 2; mt++)
#pragma unroll
                    for (int r = 0; r < 4; r++)
                        Tr[(mt * 16 + q * 4 + r) * 136 + l] = f2bf(c[mt][r] + bias_v);
                __syncthreads();
                // emit pfrag: one chunk per wave (chunkid = wid = bt*4 + ks2)
                int bt = wid >> 2, ks2 = wid & 3;
                int k0 = ks2 * 32 + (lane >> 4) * 8;
                uint4 tv = *(const uint4*)(Tr + (size_t)(bt * 16 + (lane & 15)) * 136 + k0);
                *(uint4*)(pfrag + (size_t)wid * 512 + lane * 8) = tv;
            }
        }
    }
    __syncthreads();   // pfrag/flowT visible to all waves

    // ================= Phase B: h partials — flat 32-tile stream, ring-4 ============
    bf16x8 bfr[2][4];  // pf_low fragments, held through B and C
#pragma unroll
    for (int ct = 0; ct < 2; ct++)
#pragma unroll
        for (int ks = 0; ks < 4; ks++)
            bfr[ct][ks] = *(const bf16x8*)(pfrag + (size_t)(ct * 4 + ks) * 512 + lane * 8);

    f32x4 hacc[2][2];   // [m-half][ct]
    hacc[0][0] = hacc[0][1] = hacc[1][0] = hacc[1][1] = (f32x4){0.f, 0.f, 0.f, 0.f};

    {
        bf16x8 af[4][4];
        f32x4 bvr[4];
        // preload t=0..3 (jg=0, i=t); tile row = jg*32 + wid*4 + i
#pragma unroll
        for (int t = 0; t < 4; t++) {
            const int tl = wid * 4 + t;
            const ushort* ap = pg_img + (size_t)tl * 2048;
#pragma unroll
            for (int ks = 0; ks < 4; ks++)
                af[t][ks] = *(const bf16x8*)(ap + ks * 512 + lane * 8);
            bvr[t] = *(const f32x4*)(pgb + (size_t)tl * 16 + q * 4);
        }
#pragma unroll
        for (int jg = 0; jg < 8; jg++) {
#pragma unroll
            for (int i = 0; i < 4; i++) {
                const int t = jg * 4 + i, cur = t & 3;
                const int tl = wid * 4 + i;      // p1 tile index within jg (0..31)
                const int mh = i & 1;            // tl&1 (wid*4 even)
                const int l_loc = tl >> 1;
                f32x4 bv = bvr[cur];
#pragma unroll
                for (int ct = 0; ct < 2; ct++) {
                    f32x4 cc = (f32x4){0.f, 0.f, 0.f, 0.f};
#pragma unroll
                    for (int ks = 0; ks < 4; ks++) cc = MFMA(af[cur][ks], bfr[ct][ks], cc);
                    float s = bf2f(flowT[(jg * 16 + l_loc) * 36 + ct * 16 + r15]);
#pragma unroll
                    for (int r = 0; r < 4; r++) hacc[mh][ct][r] += s * (cc[r] + bv[r]);
                }
                if (t + 4 < 32) {                // cross-jg ring reload
                    const int tn = t + 4, jgn = tn >> 2, in = tn & 3;
                    const int tln = jgn * 32 + wid * 4 + in;
                    const ushort* ap = pg_img + (size_t)tln * 2048;
#pragma unroll
                    for (int ks = 0; ks < 4; ks++)
                        af[cur][ks] = *(const bf16x8*)(ap + ks * 512 + lane * 8);
                    bvr[cur] = *(const f32x4*)(pgb + (size_t)tln * 16 + q * 4);
                }
            }
        }
    }
#pragma unroll
    for (int mh = 0; mh < 2; mh++)
#pragma unroll
        for (int ct = 0; ct < 2; ct++)
#pragma unroll
            for (int r = 0; r < 4; r++)
                hred[wid * 1024 + (mh * 16 + q * 4 + r) * 32 + ct * 16 + r15] = hacc[mh][ct][r];
    __syncthreads();
    {   // 8-partial reduce + relu -> hl [32 m][32 b]; 512 threads, 2 floats each
        int m = tid >> 4, bc = (tid & 15) * 2;
        float s0 = 0.f, s1 = 0.f;
#pragma unroll
        for (int w = 0; w < 8; w++) {
            s0 += hred[w * 1024 + m * 32 + bc];
            s1 += hred[w * 1024 + m * 32 + bc + 1];
        }
        hl[m * 32 + bc]     = fmaxf(s0, 0.f);
        hl[m * 32 + bc + 1] = fmaxf(s1, 0.f);
    }
    __syncthreads();

    // ================= Phase C: g — flat 32-tile stream, cross-lg ring-4 ============
    {
        bf16x8 afc[4][4];
        f32x4 bvc[4];
        // preload lg=0, ti=0..3: tile = 256 + m*8 + lg*2 + lt
#pragma unroll
        for (int t = 0; t < 4; t++) {
            const int m = wid + 8 * (t >> 1), lt = t & 1;
            const ushort* ap = pg_img + (size_t)(256 + m * 8 + lt) * 2048;
#pragma unroll
            for (int ks = 0; ks < 4; ks++)
                afc[t][ks] = *(const bf16x8*)(ap + ks * 512 + lane * 8);
            bvc[t] = *(const f32x4*)(pgb + 4096 + (size_t)m * 128 + lt * 16 + q * 4);
        }
#pragma unroll
        for (int lg = 0; lg < 4; lg++) {
            f32x4 gacc[2][2];   // [lt][ct]
            gacc[0][0] = gacc[0][1] = gacc[1][0] = gacc[1][1] = (f32x4){0.f, 0.f, 0.f, 0.f};
#pragma unroll
            for (int ti = 0; ti < 8; ti++) {
                const int t = lg * 8 + ti, cur = t & 3;
                const int m = wid + 8 * (ti >> 1), lt = ti & 1;
                f32x4 bv = bvc[cur];
#pragma unroll
                for (int ct = 0; ct < 2; ct++) {
                    f32x4 cc = (f32x4){0.f, 0.f, 0.f, 0.f};
#pragma unroll
                    for (int ks = 0; ks < 4; ks++) cc = MFMA(afc[cur][ks], bfr[ct][ks], cc);
                    float s = hl[m * 32 + ct * 16 + r15];
#pragma unroll
                    for (int r = 0; r < 4; r++) gacc[lt][ct][r] += s * (cc[r] + bv[r]);
                }
                if (t + 4 < 32) {                // cross-lg ring reload
                    const int tn = t + 4, lgn = tn >> 3, tin = tn & 7;
                    const int mn = wid + 8 * (tin >> 1), ltn = tin & 1;
                    const ushort* ap = pg_img + (size_t)(256 + mn * 8 + lgn * 2 + ltn) * 2048;
#pragma unroll
                    for (int ks = 0; ks < 4; ks++)
                        afc[cur][ks] = *(const bf16x8*)(ap + ks * 512 + lane * 8);
                    bvc[cur] = *(const f32x4*)(pgb + 4096 + (size_t)mn * 128 + lgn * 32 + ltn * 16 + q * 4);
                }
            }
#pragma unroll
            for (int lt = 0; lt < 2; lt++)
#pragma unroll
                for (int ct = 0; ct < 2; ct++)
#pragma unroll
                    for (int r = 0; r < 4; r++)
                        gred[wid * 1024 + (lt * 16 + q * 4 + r) * 32 + ct * 16 + r15] = gacc[lt][ct][r];
            __syncthreads();
            if (tid < 128) {   // 8-partial reduce + emit gfrag chunk (bt, ks=lg)
                int bt = tid >> 6, ln = tid & 63;
                int b_loc = bt * 16 + (ln & 15);
                int l0 = (ln >> 4) * 8;
                ushort tmp[8];
#pragma unroll
                for (int e = 0; e < 8; e++) {
                    const float* gp = gred + (size_t)(l0 + e) * 32 + b_loc;
                    float s = 0.f;
#pragma unroll
                    for (int w = 0; w < 8; w++) s += gp[w * 1024];
                    tmp[e] = f2bf(s);
                }
                ushort4 lo = {tmp[0], tmp[1], tmp[2], tmp[3]};
                ushort4 hi = {tmp[4], tmp[5], tmp[6], tmp[7]};
                ushort* dst = gfrag + (size_t)(bt * 4 + lg) * 512 + ln * 8;
                ((ushort4*)dst)[0] = lo;
                ((ushort4*)dst)[1] = hi;
            }
            __syncthreads();   // gred reuse (and gfrag ready after last lg)
        }
    }

    // ================= Phase D: out = g@W2^T + b2 + f + pf (ring-2 over nb) =========
    {
        bf16x8 afg[2][4];
#pragma unroll
        for (int mtl = 0; mtl < 2; mtl++)
#pragma unroll
            for (int ks = 0; ks < 4; ks++)
                afg[mtl][ks] = *(const bf16x8*)(gfrag + (size_t)(mtl * 4 + ks) * 512 + lane * 8);

        bf16x8 w2r[2][2][4];   // [buf][nt][ks]
#pragma unroll
        for (int nt = 0; nt < 2; nt++)
#pragma unroll
            for (int ks = 0; ks < 4; ks++)
                w2r[0][nt][ks] = *(const bf16x8*)(w2_img + (size_t)((wid * 2 + nt) * 4 + ks) * 512 + lane * 8);

#pragma unroll
        for (int nb = 0; nb < 4; nb++) {
            const int cur = nb & 1;
            const int n0 = nb * 256;
            // early epilogue loads: land before the post-Ls barrier
            float4 fa[4], pa[4];
#pragma unroll
            for (int rr = 0; rr < 4; rr++) {
                const int b = b0 + wid * 4 + rr;
                const size_t gbase = (size_t)b * 1024 + n0 + lane * 4;
                fa[rr] = *(const float4*)(f + gbase);
                pa[rr] = *(const float4*)(pf + gbase);
            }
            float bias_v2[2];
#pragma unroll
            for (int nt = 0; nt < 2; nt++) bias_v2[nt] = b2[nb * 256 + wid * 32 + nt * 16 + r15];
#pragma unroll
            for (int nt = 0; nt < 2; nt++) {
#pragma unroll
                for (int mtl = 0; mtl < 2; mtl++) {
                    f32x4 cc = (f32x4){0.f, 0.f, 0.f, 0.f};
#pragma unroll
                    for (int ks = 0; ks < 4; ks++) cc = MFMA(afg[mtl][ks], w2r[cur][nt][ks], cc);
                    const int nloc = wid * 32 + nt * 16 + r15;        // 0..255
                    const int chunk = nloc >> 5, within = nloc & 31;
#pragma unroll
                    for (int r = 0; r < 4; r++)
                        Ls[(size_t)(mtl * 16 + q * 4 + r) * 288 + chunk * 36 + within] = cc[r] + bias_v2[nt];
                }
            }
            if (nb < 3) {      // prefetch next nb's w2 fragments during barrier window
#pragma unroll
                for (int nt = 0; nt < 2; nt++)
#pragma unroll
                    for (int ks = 0; ks < 4; ks++)
                        w2r[cur ^ 1][nt][ks] = *(const bf16x8*)(w2_img + (size_t)(((nb + 1) * 16 + wid * 2 + nt) * 4 + ks) * 512 + lane * 8);
            }
            __syncthreads();
            {   // wave-contiguous epilogue: wave w rows w*4..+4, lane i <-> n0+4i
                const float* ls = Ls + (size_t)(wid * 4) * 288 + (lane >> 3) * 36 + (lane & 7) * 4;
#pragma unroll
                for (int rr = 0; rr < 4; rr++) {
                    const int b = b0 + wid * 4 + rr;
                    const size_t gbase = (size_t)b * 1024 + n0 + lane * 4;
                    float4 lv = *(const float4*)(ls + rr * 288);
                    float4 o;
                    o.x = lv.x + fa[rr].x + pa[rr].x; o.y = lv.y + fa[rr].y + pa[rr].y;
                    o.z = lv.z + fa[rr].z + pa[rr].z; o.w = lv.w + fa[rr].w + pa[rr].w;
                    *(float4*)(out + gbase) = o;
                }
            }
            __syncthreads();   // Ls reuse protection for next nb
        }
    }
}

// ---------------- launch ----------------
extern "C" void kernel_launch(void* const* d_in, const int* in_sizes, int n_in,
                              void* d_out, int out_size, void* d_ws, size_t ws_size,
                              hipStream_t stream)
{
    const float* f    = (const float*)d_in[0];
    const float* pf   = (const float*)d_in[1];
    const float* wf   = (const float*)d_in[2];
    const float* bfb  = (const float*)d_in[3];
    const float* wpf  = (const float*)d_in[4];
    const float* bpfb = (const float*)d_in[5];
    const float* w2   = (const float*)d_in[6];
    const float* b2   = (const float*)d_in[7];
    const float* pgw  = (const float*)d_in[8];
    const float* pgb  = (const float*)d_in[9];

    char* ws = (char*)d_ws;
    ushort* pg_img = (ushort*)(ws + 0);          // 2 MB
    ushort* w_img  = (ushort*)(ws + 2097152);    // 512 KB
    ushort* w2_img = (ushort*)(ws + 2621440);    // 256 KB
    float*  out    = (float*)d_out;

    k0_convert<<<dim3(704), dim3(256), 0, stream>>>(pgw, wf, wpf, w2, pg_img, w_img, w2_img);
    mega<<<dim3(256), dim3(512), 0, stream>>>(f, pf, w_img, bfb, bpfb,
                                              pg_img, pgb, w2_img, b2, out);
}